// Round 2
// baseline (1695.458 us; speedup 1.0000x reference)
//
#include <hip/hip_runtime.h>

typedef unsigned short ushort_t;
typedef __attribute__((ext_vector_type(8))) __bf16 bf8v;
typedef __attribute__((ext_vector_type(4))) float f4v;
typedef __attribute__((ext_vector_type(4))) unsigned short us4v;

#define MFMA(a, b, c) __builtin_amdgcn_mfma_f32_16x16x32_bf16((a), (b), (c), 0, 0, 0)

#define B_TOT 8192
#define T_STEPS 16
#define M_TILE 16    // 16 rows/block -> 512 blocks -> 2 blocks/CU (was 1)
#define LDH 264      // 256 + 8 pad (16B-aligned rows, bank-spread)
#define LDS_SM 72    // 64 + 8 pad
#define LDMID 168    // 160 + 8 pad

// bf16 weight workspace offsets (ushort units)
#define OW1I 0
#define OW1H 16384
#define OWF1 81920
#define OW1O 98304
#define OW2I 114688
#define OW2H 131072
#define OWF2 196608
#define OW2O 212992
#define OW3I 229376   // [256][160] permuted: 0-63=out1 cols, 64-127=out2 cols, 128-129=cue, 130-159=0
#define OW3H 270336
#define OW3O 335872
#define OWFC 352256   // [16][64], rows 2..15 zero
#define WS_TOTAL 353280

// output offsets (float units), concatenated in reference return order
#define O_OSEQ 0
#define O_H1   262144
#define O_H2   2359296
#define O_H3   4456448
#define O_H4   6553600
#define O_O1   7077888
#define O_O2   15466496
#define O_CUE  23855104
#define O_F1   24117248
#define O_F2   57671680
#define O_OFA  91226112

__device__ __forceinline__ ushort_t f2bf(float f) {
  union { float f; unsigned u; } v; v.f = f;
  unsigned r = v.u + 0x7fffu + ((v.u >> 16) & 1u);  // round-to-nearest-even
  return (ushort_t)(r >> 16);
}

__device__ __forceinline__ float fast_tanh(float x) {
  // tanh(x) = 1 - 2/(e^{2x}+1); exact at +/-inf, ~1e-6 abs err
  float e = __expf(2.0f * x);
  return 1.0f - 2.0f * __builtin_amdgcn_rcpf(e + 1.0f);
}

__device__ __forceinline__ void store_bf4(ushort_t* p, f4v v) {
  us4v q;
  q[0] = f2bf(v[0]); q[1] = f2bf(v[1]); q[2] = f2bf(v[2]); q[3] = f2bf(v[3]);
  *(us4v*)p = q;
}

// streaming (non-temporal) helpers: keep L2 for the weight working set
__device__ __forceinline__ void nt_st4(float* p, f4v v) {
  __builtin_nontemporal_store(v, (f4v*)p);
}
__device__ __forceinline__ f4v nt_ld4(const float* p) {
  return __builtin_nontemporal_load((const f4v*)p);
}

__global__ void prep_kernel(const float* __restrict__ W1i, const float* __restrict__ W1h,
                            const float* __restrict__ Wf1, const float* __restrict__ W1o,
                            const float* __restrict__ W2i, const float* __restrict__ W2h,
                            const float* __restrict__ Wf2, const float* __restrict__ W2o,
                            const float* __restrict__ W3i, const float* __restrict__ W3h,
                            const float* __restrict__ W3o, const float* __restrict__ Wfc,
                            ushort_t* __restrict__ ws) {
  int i = blockIdx.x * blockDim.x + threadIdx.x;
  if (i >= WS_TOTAL) return;
  float v;
  if (i < OW1H)       v = W1i[i - OW1I];
  else if (i < OWF1)  v = W1h[i - OW1H];
  else if (i < OW1O)  v = Wf1[i - OWF1];
  else if (i < OW2I)  v = W1o[i - OW1O];
  else if (i < OW2H)  v = W2i[i - OW2I];
  else if (i < OWF2)  v = W2h[i - OW2H];
  else if (i < OW2O)  v = Wf2[i - OWF2];
  else if (i < OW3I)  v = W2o[i - OW2O];
  else if (i < OW3H) {
    int idx = i - OW3I; int j = idx / 160; int k = idx - j * 160;
    if (k < 64)       v = W3i[j * 130 + 2 + k];
    else if (k < 128) v = W3i[j * 130 + 66 + (k - 64)];
    else if (k < 130) v = W3i[j * 130 + (k - 128)];
    else              v = 0.0f;
  }
  else if (i < OW3O)  v = W3h[i - OW3H];
  else if (i < OWFC)  v = W3o[i - OW3O];
  else {
    int idx = i - OWFC; int j = idx / 64; int k = idx - j * 64;
    v = (j < 2) ? Wfc[j * 64 + k] : 0.0f;
  }
  ws[i] = f2bf(v);
}

// 512 threads (8 waves), M_TILE=16: per-wave MFMA count per phase identical to the
// old M_TILE=32 kernel (the m-tile loop folded into a 2x bigger grid).
// __launch_bounds__(512,4): 4 waves/EU => VGPR<=128 => 2 blocks/CU co-resident
// (LDS 37632 B/block, 75264 B for 2 blocks).
__launch_bounds__(512, 4)
__global__ void rnn_kernel(const float* __restrict__ x, const float* __restrict__ cue,
                           const float* __restrict__ hc1, const float* __restrict__ hc2,
                           const float* __restrict__ hc3, const float* __restrict__ hc4,
                           const float* __restrict__ b1i, const float* __restrict__ b1h,
                           const float* __restrict__ bf1p, const float* __restrict__ b1o,
                           const float* __restrict__ b2i, const float* __restrict__ b2h,
                           const float* __restrict__ bf2p, const float* __restrict__ b2o,
                           const float* __restrict__ b3i, const float* __restrict__ b3h,
                           const float* __restrict__ b3o, const float* __restrict__ bfc,
                           const ushort_t* __restrict__ ws, float* __restrict__ out) {
  __shared__ ushort_t hs1[M_TILE * LDH], hs2[M_TILE * LDH], hs3[M_TILE * LDH];
  __shared__ ushort_t h4s[M_TILE * LDS_SM], xs[M_TILE * LDS_SM], ofs[M_TILE * LDS_SM];
  __shared__ ushort_t mid[M_TILE * LDMID];

  const int tid  = threadIdx.x;
  const int m0   = blockIdx.x * M_TILE;
  const int lane = tid & 63;
  const int w    = tid >> 6;       // wave 0..7
  const int ln   = lane & 15;
  const int quad = lane >> 4;
  const int koff = quad * 8;
  const int jt0  = 2 * w;          // first j-tile for 256-wide GEMMs (8 waves x 2 = 16 tiles)

  // ---------------- init: states -> LDS (bf16), vectorized nt loads ----------------
  for (int i = tid; i < M_TILE * 64; i += 512) {   // 1024 f4v-chunks of 256-wide states
    int m = i >> 6, j4 = (i & 63) * 4;
    store_bf4(&hs1[m * LDH + j4], nt_ld4(&hc1[(size_t)(m0 + m) * 256 + j4]));
    store_bf4(&hs2[m * LDH + j4], nt_ld4(&hc2[(size_t)(m0 + m) * 256 + j4]));
    store_bf4(&hs3[m * LDH + j4], nt_ld4(&hc3[(size_t)(m0 + m) * 256 + j4]));
  }
  if (tid < M_TILE * 16) {                         // 256 f4v-chunks of hc4
    int m = tid >> 4, j4 = (tid & 15) * 4;
    store_bf4(&h4s[m * LDS_SM + j4], nt_ld4(&hc4[(size_t)(m0 + m) * 64 + j4]));
  }
  for (int i = tid; i < M_TILE * LDMID; i += 512) mid[i] = 0;
  if (tid < 256) {
    // cue_arr output: 256 threads = 16 t x 16 rows
    int t = tid >> 4, r = tid & 15;
    float c = cue[m0 + r];
    float* oc = out + O_CUE + ((size_t)t * B_TOT + m0 + r) * 2;
    __builtin_nontemporal_store(c * 10.0f, oc);
    __builtin_nontemporal_store(10.0f * fabsf(c - 1.0f), oc + 1);
  }
  __syncthreads();
  if (tid < M_TILE) {
    float c = cue[m0 + tid];
    mid[tid * LDMID + 128] = f2bf(c * 10.0f);
    mid[tid * LDMID + 129] = f2bf(10.0f * fabsf(c - 1.0f));
  }

  // ---------------- per-thread bias registers (t-invariant) ----------------
  f4v bf1v[2], bf2v[2], bih1v[2], bih2v[2], b3shv[2];
#pragma unroll
  for (int i = 0; i < 2; ++i) {
    int j0 = (jt0 + i) * 16 + quad * 4;
#pragma unroll
    for (int r = 0; r < 4; ++r) {
      bf1v[i][r]  = bf1p[j0 + r];
      bf2v[i][r]  = bf2p[j0 + r];
      bih1v[i][r] = b1i[j0 + r] + b1h[j0 + r];
      bih2v[i][r] = b2i[j0 + r] + b2h[j0 + r];
      b3shv[i][r] = b3i[j0 + r] + b3h[j0 + r];
    }
  }
  // S3 (out1/out2): waves 0-3 -> out1 (stack1), waves 4-7 -> out2 (stack2); 1 j-tile each
  const int jto3 = w & 3;
  const int j0o3 = jto3 * 16 + quad * 4;
  const bool isOut2 = (w >= 4);
  f4v bo3v;
#pragma unroll
  for (int r = 0; r < 4; ++r) bo3v[r] = isOut2 ? b2o[j0o3 + r] : b1o[j0o3 + r];
  // S5 (o GEMM): waves 0-3 only, j-tile = w
  const int jto5 = w & 3;
  const int j0o5 = jto5 * 16 + quad * 4;
  f4v b3ov;
#pragma unroll
  for (int r = 0; r < 4; ++r) b3ov[r] = b3o[j0o5 + r];
  const float bfcv0 = bfc[0], bfcv1 = bfc[1];

  __syncthreads();

  f4v acc1[2], acc2[2], acc3[2];

  for (int t = 0; t < T_STEPS; ++t) {
    // ======== S0: stage x[t] tile -> xs ; feed1/feed2 GEMMs (read h4s) ========
    if (tid < 256) {
      int r = tid >> 4, c4 = (tid & 15) * 4;
      const float* xp = x + ((size_t)t * B_TOT + m0 + r) * 64 + c4;
      store_bf4(&xs[r * LDS_SM + c4], nt_ld4(xp));
    }
    {
      f4v aF1[2], aF2[2];
#pragma unroll
      for (int i = 0; i < 2; ++i) { aF1[i] = bf1v[i]; aF2[i] = bf2v[i]; }
#pragma unroll
      for (int kk = 0; kk < 64; kk += 32) {
        bf8v b0 = *(const bf8v*)&h4s[ln * LDS_SM + kk + koff];
#pragma unroll
        for (int i = 0; i < 2; ++i) {
          const int ar = ((jt0 + i) * 16 + ln) * 64 + kk + koff;
          bf8v a1 = *(const bf8v*)&ws[OWF1 + ar];
          bf8v a2 = *(const bf8v*)&ws[OWF2 + ar];
          aF1[i] = MFMA(a1, b0, aF1[i]);
          aF2[i] = MFMA(a2, b0, aF2[i]);
        }
      }
      // epilogue: write f1/f2 (pre-tanh), seed acc1/acc2 with tanh(feed)+bias, seed acc3 with bias
#pragma unroll
      for (int i = 0; i < 2; ++i) {
        int j0 = (jt0 + i) * 16 + quad * 4;
        size_t rowoff = ((size_t)t * B_TOT + m0 + ln) * 256 + j0;
        nt_st4(out + O_F1 + rowoff, aF1[i]);
        nt_st4(out + O_F2 + rowoff, aF2[i]);
        f4v t1, t2;
#pragma unroll
        for (int r = 0; r < 4; ++r) {
          t1[r] = fast_tanh(aF1[i][r]) + bih1v[i][r];
          t2[r] = fast_tanh(aF2[i][r]) + bih2v[i][r];
        }
        acc1[i] = t1; acc2[i] = t2; acc3[i] = b3shv[i];
      }
    }
    __syncthreads();  // SYNC1: xs ready

    // ======== S1: h1n/h2n GEMMs (ih from xs, hh from hs1/hs2) + hh3 into acc3 ========
#pragma unroll
    for (int kk = 0; kk < 64; kk += 32) {
      bf8v b0 = *(const bf8v*)&xs[ln * LDS_SM + kk + koff];
#pragma unroll
      for (int i = 0; i < 2; ++i) {
        const int ar = ((jt0 + i) * 16 + ln) * 64 + kk + koff;
        bf8v a1 = *(const bf8v*)&ws[OW1I + ar];
        bf8v a2 = *(const bf8v*)&ws[OW2I + ar];
        acc1[i] = MFMA(a1, b0, acc1[i]);
        acc2[i] = MFMA(a2, b0, acc2[i]);
      }
    }
#pragma unroll
    for (int kk = 0; kk < 256; kk += 32) {
      bf8v q1 = *(const bf8v*)&hs1[ln * LDH + kk + koff];
      bf8v q2 = *(const bf8v*)&hs2[ln * LDH + kk + koff];
      bf8v q3 = *(const bf8v*)&hs3[ln * LDH + kk + koff];
#pragma unroll
      for (int i = 0; i < 2; ++i) {
        const int ar = ((jt0 + i) * 16 + ln) * 256 + kk + koff;
        bf8v a1 = *(const bf8v*)&ws[OW1H + ar];
        bf8v a2 = *(const bf8v*)&ws[OW2H + ar];
        bf8v a3 = *(const bf8v*)&ws[OW3H + ar];
        acc1[i] = MFMA(a1, q1, acc1[i]);
        acc2[i] = MFMA(a2, q2, acc2[i]);
        acc3[i] = MFMA(a3, q3, acc3[i]);
      }
    }
#pragma unroll
    for (int i = 0; i < 2; ++i) {
#pragma unroll
      for (int r = 0; r < 4; ++r) {
        acc1[i][r] = fast_tanh(acc1[i][r]);
        acc2[i][r] = fast_tanh(acc2[i][r]);
      }
    }
    if (t == T_STEPS - 1) {
#pragma unroll
      for (int i = 0; i < 2; ++i) {
        int j0 = (jt0 + i) * 16 + quad * 4;
        *(f4v*)(out + O_H1 + (size_t)(m0 + ln) * 256 + j0) = acc1[i];
        *(f4v*)(out + O_H2 + (size_t)(m0 + ln) * 256 + j0) = acc2[i];
      }
    }
    __syncthreads();  // SYNC2: all reads of old hs1/hs2/hs3 done

    // ======== S2: write back new h1/h2 states ========
#pragma unroll
    for (int i = 0; i < 2; ++i) {
      int j0 = (jt0 + i) * 16 + quad * 4;
      store_bf4(&hs1[ln * LDH + j0], acc1[i]);
      store_bf4(&hs2[ln * LDH + j0], acc2[i]);
    }
    __syncthreads();  // SYNC3: new hs1/hs2 ready

    // ======== S3: out1 (waves 0-3) / out2 (waves 4-7), N=64, K=256 ========
    {
      const ushort_t* hsrc = isOut2 ? hs2 : hs1;
      const int wbase = isOut2 ? OW2O : OW1O;
      f4v aO = bo3v;
#pragma unroll
      for (int kk = 0; kk < 256; kk += 32) {
        bf8v b0 = *(const bf8v*)&hsrc[ln * LDH + kk + koff];
        bf8v a  = *(const bf8v*)&ws[wbase + (jto3 * 16 + ln) * 256 + kk + koff];
        aO = MFMA(a, b0, aO);
      }
#pragma unroll
      for (int r = 0; r < 4; ++r) aO[r] = fast_tanh(aO[r]);
      size_t ob = ((size_t)t * B_TOT + m0 + ln) * 64 + j0o3;
      nt_st4(out + (isOut2 ? O_O2 : O_O1) + ob, aO);
      store_bf4(&mid[ln * LDMID + (isOut2 ? 64 : 0) + j0o3], aO);
    }
    __syncthreads();  // SYNC4: mid ready

    // ======== S4: acc3 += W3i_perm x mid (K=160); tanh; write hs3 ========
#pragma unroll
    for (int kk = 0; kk < 160; kk += 32) {
      bf8v b0 = *(const bf8v*)&mid[ln * LDMID + kk + koff];
#pragma unroll
      for (int i = 0; i < 2; ++i) {
        bf8v a = *(const bf8v*)&ws[OW3I + ((jt0 + i) * 16 + ln) * 160 + kk + koff];
        acc3[i] = MFMA(a, b0, acc3[i]);
      }
    }
#pragma unroll
    for (int i = 0; i < 2; ++i) {
#pragma unroll
      for (int r = 0; r < 4; ++r) acc3[i][r] = fast_tanh(acc3[i][r]);
      int j0 = (jt0 + i) * 16 + quad * 4;
      if (t == T_STEPS - 1)
        *(f4v*)(out + O_H3 + (size_t)(m0 + ln) * 256 + j0) = acc3[i];
      store_bf4(&hs3[ln * LDH + j0], acc3[i]);  // old hs3 readers finished at S1 (SYNC2+)
    }
    __syncthreads();  // SYNC5: new hs3 ready

    // ======== S5: o = h3n @ W3o.T + b3o (N=64, waves 0-3); -> h4s, ofa, ofs, (h4 final) ========
    if (w < 4) {
      f4v aO = b3ov;
#pragma unroll
      for (int kk = 0; kk < 256; kk += 32) {
        bf8v b = *(const bf8v*)&hs3[ln * LDH + kk + koff];
        bf8v a = *(const bf8v*)&ws[OW3O + (jto5 * 16 + ln) * 256 + kk + koff];
        aO = MFMA(a, b, aO);
      }
      store_bf4(&h4s[ln * LDS_SM + j0o5], aO);  // h4s readers (S0) finished long ago
      if (t == T_STEPS - 1)
        *(f4v*)(out + O_H4 + (size_t)(m0 + ln) * 64 + j0o5) = aO;
      f4v rl;
#pragma unroll
      for (int r = 0; r < 4; ++r) rl[r] = fmaxf(aO[r], 0.0f);
      nt_st4(out + O_OFA + ((size_t)t * B_TOT + m0 + ln) * 64 + j0o5, rl);
      store_bf4(&ofs[ln * LDS_SM + j0o5], rl);
    }
    __syncthreads();  // SYNC6: ofs/h4s ready

    // ======== S6: outf = relu(o) @ Wfc.T + bfc -> oseq (wave 0 only) ========
    if (w == 0) {
      f4v aFc;
      aFc[0] = (quad == 0) ? bfcv0 : 0.0f;
      aFc[1] = (quad == 0) ? bfcv1 : 0.0f;
      aFc[2] = 0.0f; aFc[3] = 0.0f;
#pragma unroll
      for (int kk = 0; kk < 64; kk += 32) {
        bf8v b = *(const bf8v*)&ofs[ln * LDS_SM + kk + koff];
        bf8v a = *(const bf8v*)&ws[OWFC + ln * 64 + kk + koff];
        aFc = MFMA(a, b, aFc);
      }
      if (quad == 0) {
        float* po = out + O_OSEQ + ((size_t)t * B_TOT + m0 + ln) * 2;
        __builtin_nontemporal_store(aFc[0], po);
        __builtin_nontemporal_store(aFc[1], po + 1);
      }
    }
    // no barrier needed: next S0 writes xs (last read S1, covered by SYNC2+)
    // and reads h4s (written S5, covered by SYNC6)
  }
}

extern "C" void kernel_launch(void* const* d_in, const int* in_sizes, int n_in,
                              void* d_out, int out_size, void* d_ws, size_t ws_size,
                              hipStream_t stream) {
  const float* x   = (const float*)d_in[0];
  const float* cue = (const float*)d_in[1];
  const float* hc1 = (const float*)d_in[2];
  const float* hc2 = (const float*)d_in[3];
  const float* hc3 = (const float*)d_in[4];
  const float* hc4 = (const float*)d_in[5];
  const float* W1i = (const float*)d_in[6];
  const float* b1i = (const float*)d_in[7];
  const float* W1h = (const float*)d_in[8];
  const float* b1h = (const float*)d_in[9];
  const float* Wf1 = (const float*)d_in[10];
  const float* bf1 = (const float*)d_in[11];
  const float* W1o = (const float*)d_in[12];
  const float* b1o = (const float*)d_in[13];
  const float* W2i = (const float*)d_in[14];
  const float* b2i = (const float*)d_in[15];
  const float* W2h = (const float*)d_in[16];
  const float* b2h = (const float*)d_in[17];
  const float* Wf2 = (const float*)d_in[18];
  const float* bf2 = (const float*)d_in[19];
  const float* W2o = (const float*)d_in[20];
  const float* b2o = (const float*)d_in[21];
  const float* W3i = (const float*)d_in[22];
  const float* b3i = (const float*)d_in[23];
  const float* W3h = (const float*)d_in[24];
  const float* b3h = (const float*)d_in[25];
  const float* W3o = (const float*)d_in[26];
  const float* b3o = (const float*)d_in[27];
  const float* Wfc = (const float*)d_in[28];
  const float* bfc = (const float*)d_in[29];

  ushort_t* ws = (ushort_t*)d_ws;
  float* out = (float*)d_out;

  prep_kernel<<<(WS_TOTAL + 511) / 512, 512, 0, stream>>>(
      W1i, W1h, Wf1, W1o, W2i, W2h, Wf2, W2o, W3i, W3h, W3o, Wfc, ws);

  rnn_kernel<<<B_TOT / M_TILE, 512, 0, stream>>>(
      x, cue, hc1, hc2, hc3, hc4,
      b1i, b1h, bf1, b1o, b2i, b2h, bf2, b2o, b3i, b3h, b3o, bfc,
      ws, out);
}

// Round 3
// 988.103 us; speedup vs baseline: 1.7159x; 1.7159x over previous
//
#include <hip/hip_runtime.h>

typedef unsigned short ushort_t;
typedef __attribute__((ext_vector_type(8))) __bf16 bf8v;
typedef __attribute__((ext_vector_type(4))) float f4v;
typedef __attribute__((ext_vector_type(4))) unsigned short us4v;

#define MFMA(a, b, c) __builtin_amdgcn_mfma_f32_16x16x32_bf16((a), (b), (c), 0, 0, 0)

#define B_TOT 8192
#define T_STEPS 16
#define M_TILE 32
#define LDH 264      // 256 + 8 pad (16B-aligned rows, bank-spread)
#define LDS_SM 72    // 64 + 8 pad
#define LDMID 168    // 160 + 8 pad

// bf16 weight workspace offsets (ushort units)
#define OW1I 0
#define OW1H 16384
#define OWF1 81920
#define OW1O 98304
#define OW2I 114688
#define OW2H 131072
#define OWF2 196608
#define OW2O 212992
#define OW3I 229376   // [256][160] permuted: 0-63=out1 cols, 64-127=out2 cols, 128-129=cue, 130-159=0
#define OW3H 270336
#define OW3O 335872
#define OWFC 352256   // [16][64], rows 2..15 zero
#define WS_TOTAL 353280

// output offsets (float units), concatenated in reference return order
#define O_OSEQ 0
#define O_H1   262144
#define O_H2   2359296
#define O_H3   4456448
#define O_H4   6553600
#define O_O1   7077888
#define O_O2   15466496
#define O_CUE  23855104
#define O_F1   24117248
#define O_F2   57671680
#define O_OFA  91226112

__device__ __forceinline__ ushort_t f2bf(float f) {
  union { float f; unsigned u; } v; v.f = f;
  unsigned r = v.u + 0x7fffu + ((v.u >> 16) & 1u);  // round-to-nearest-even
  return (ushort_t)(r >> 16);
}

__device__ __forceinline__ float fast_tanh(float x) {
  // tanh(x) = 1 - 2/(e^{2x}+1); exact at +/-inf, ~1e-6 abs err
  float e = __expf(2.0f * x);
  return 1.0f - 2.0f * __builtin_amdgcn_rcpf(e + 1.0f);
}

__device__ __forceinline__ void store_bf4(ushort_t* p, f4v v) {
  us4v q;
  q[0] = f2bf(v[0]); q[1] = f2bf(v[1]); q[2] = f2bf(v[2]); q[3] = f2bf(v[3]);
  *(us4v*)p = q;
}

// streaming (non-temporal) helpers: keep L2 for the weight working set
__device__ __forceinline__ void nt_st4(float* p, f4v v) {
  __builtin_nontemporal_store(v, (f4v*)p);
}
__device__ __forceinline__ f4v nt_ld4(const float* p) {
  return __builtin_nontemporal_load((const f4v*)p);
}

__global__ void prep_kernel(const float* __restrict__ W1i, const float* __restrict__ W1h,
                            const float* __restrict__ Wf1, const float* __restrict__ W1o,
                            const float* __restrict__ W2i, const float* __restrict__ W2h,
                            const float* __restrict__ Wf2, const float* __restrict__ W2o,
                            const float* __restrict__ W3i, const float* __restrict__ W3h,
                            const float* __restrict__ W3o, const float* __restrict__ Wfc,
                            ushort_t* __restrict__ ws) {
  int i = blockIdx.x * blockDim.x + threadIdx.x;
  if (i >= WS_TOTAL) return;
  float v;
  if (i < OW1H)       v = W1i[i - OW1I];
  else if (i < OWF1)  v = W1h[i - OW1H];
  else if (i < OW1O)  v = Wf1[i - OWF1];
  else if (i < OW2I)  v = W1o[i - OW1O];
  else if (i < OW2H)  v = W2i[i - OW2I];
  else if (i < OWF2)  v = W2h[i - OW2H];
  else if (i < OW2O)  v = Wf2[i - OWF2];
  else if (i < OW3I)  v = W2o[i - OW2O];
  else if (i < OW3H) {
    int idx = i - OW3I; int j = idx / 160; int k = idx - j * 160;
    if (k < 64)       v = W3i[j * 130 + 2 + k];
    else if (k < 128) v = W3i[j * 130 + 66 + (k - 64)];
    else if (k < 130) v = W3i[j * 130 + (k - 128)];
    else              v = 0.0f;
  }
  else if (i < OW3O)  v = W3h[i - OW3H];
  else if (i < OWFC)  v = W3o[i - OW3O];
  else {
    int idx = i - OWFC; int j = idx / 64; int k = idx - j * 64;
    v = (j < 2) ? Wfc[j * 64 + k] : 0.0f;
  }
  ws[i] = f2bf(v);
}

// M_TILE=32, 256 blocks = 1 block/CU, 8 waves.
// __launch_bounds__(512, 2): 2 waves/EU min => compiler may use up to 256 VGPR/wave,
// giving it room to keep many independent 16B weight loads in flight per phase
// (round-0's 128-VGPR build was load-latency serialized; the (512,4) build at 64 VGPR
// was catastrophically so).
__launch_bounds__(512, 2)
__global__ void rnn_kernel(const float* __restrict__ x, const float* __restrict__ cue,
                           const float* __restrict__ hc1, const float* __restrict__ hc2,
                           const float* __restrict__ hc3, const float* __restrict__ hc4,
                           const float* __restrict__ b1i, const float* __restrict__ b1h,
                           const float* __restrict__ bf1p, const float* __restrict__ b1o,
                           const float* __restrict__ b2i, const float* __restrict__ b2h,
                           const float* __restrict__ bf2p, const float* __restrict__ b2o,
                           const float* __restrict__ b3i, const float* __restrict__ b3h,
                           const float* __restrict__ b3o, const float* __restrict__ bfc,
                           const ushort_t* __restrict__ ws, float* __restrict__ out) {
  __shared__ ushort_t hs1[M_TILE * LDH], hs2[M_TILE * LDH], hs3[M_TILE * LDH];
  __shared__ ushort_t h4s[M_TILE * LDS_SM], xs[M_TILE * LDS_SM], ofs[M_TILE * LDS_SM];
  __shared__ ushort_t mid[M_TILE * LDMID];

  const int tid  = threadIdx.x;
  const int m0   = blockIdx.x * M_TILE;
  const int lane = tid & 63;
  const int w    = tid >> 6;       // wave 0..7
  const int ln   = lane & 15;
  const int quad = lane >> 4;
  const int koff = quad * 8;
  const int jt0  = 2 * w;          // first j-tile for 256-wide GEMMs

  // ---------------- init: states -> LDS (bf16), vectorized nt loads ----------------
  for (int i = tid; i < M_TILE * 64; i += 512) {   // 2048 f4v-chunks of 256-wide states
    int m = i >> 6, j4 = (i & 63) * 4;
    store_bf4(&hs1[m * LDH + j4], nt_ld4(&hc1[(size_t)(m0 + m) * 256 + j4]));
    store_bf4(&hs2[m * LDH + j4], nt_ld4(&hc2[(size_t)(m0 + m) * 256 + j4]));
    store_bf4(&hs3[m * LDH + j4], nt_ld4(&hc3[(size_t)(m0 + m) * 256 + j4]));
  }
  {                                                // 512 f4v-chunks of hc4 (exactly 512 threads)
    int m = tid >> 4, j4 = (tid & 15) * 4;
    store_bf4(&h4s[m * LDS_SM + j4], nt_ld4(&hc4[(size_t)(m0 + m) * 64 + j4]));
  }
  for (int i = tid; i < M_TILE * LDMID; i += 512) mid[i] = 0;
  {
    // cue_arr output: 512 threads = 16 t x 32 rows
    int t = tid >> 5, r = tid & 31;
    float c = cue[m0 + r];
    float* oc = out + O_CUE + ((size_t)t * B_TOT + m0 + r) * 2;
    __builtin_nontemporal_store(c * 10.0f, oc);
    __builtin_nontemporal_store(10.0f * fabsf(c - 1.0f), oc + 1);
  }
  __syncthreads();
  if (tid < M_TILE) {
    float c = cue[m0 + tid];
    mid[tid * LDMID + 128] = f2bf(c * 10.0f);
    mid[tid * LDMID + 129] = f2bf(10.0f * fabsf(c - 1.0f));
  }

  // ---------------- per-thread bias registers (t-invariant) ----------------
  f4v bf1v[2], bf2v[2], bih1v[2], bih2v[2], b3shv[2];
#pragma unroll
  for (int i = 0; i < 2; ++i) {
    int j0 = (jt0 + i) * 16 + quad * 4;
#pragma unroll
    for (int r = 0; r < 4; ++r) {
      bf1v[i][r]  = bf1p[j0 + r];
      bf2v[i][r]  = bf2p[j0 + r];
      bih1v[i][r] = b1i[j0 + r] + b1h[j0 + r];
      bih2v[i][r] = b2i[j0 + r] + b2h[j0 + r];
      b3shv[i][r] = b3i[j0 + r] + b3h[j0 + r];
    }
  }
  // S3 (out1/out2): waves 0-3 -> out1 (stack1), waves 4-7 -> out2 (stack2)
  const int jto3 = w & 3;
  const int j0o3 = jto3 * 16 + quad * 4;
  const bool isOut2 = (w >= 4);
  f4v bo3v;
#pragma unroll
  for (int r = 0; r < 4; ++r) bo3v[r] = isOut2 ? b2o[j0o3 + r] : b1o[j0o3 + r];
  // S5 (o GEMM): jto5 = w>>1, mto5 = w&1
  const int jto5 = w >> 1;
  const int j0o5 = jto5 * 16 + quad * 4;
  const int mo5  = (w & 1) * 16 + ln;
  f4v b3ov;
#pragma unroll
  for (int r = 0; r < 4; ++r) b3ov[r] = b3o[j0o5 + r];
  const float bfcv0 = bfc[0], bfcv1 = bfc[1];

  __syncthreads();

  f4v acc1[2][2], acc2[2][2], acc3[2][2];

  for (int t = 0; t < T_STEPS; ++t) {
    // ======== S0: stage x[t] tile -> xs ; feed1/feed2 GEMMs (read h4s) ========
    {
      int r = tid >> 4, c4 = (tid & 15) * 4;
      const float* xp = x + ((size_t)t * B_TOT + m0 + r) * 64 + c4;
      store_bf4(&xs[r * LDS_SM + c4], nt_ld4(xp));
    }
    {
      f4v aF1[2][2], aF2[2][2];
#pragma unroll
      for (int i = 0; i < 2; ++i) {
#pragma unroll
        for (int mt = 0; mt < 2; ++mt) { aF1[i][mt] = bf1v[i]; aF2[i][mt] = bf2v[i]; }
      }
#pragma unroll
      for (int kk = 0; kk < 64; kk += 32) {
        bf8v b0 = *(const bf8v*)&h4s[ln * LDS_SM + kk + koff];
        bf8v b1 = *(const bf8v*)&h4s[(16 + ln) * LDS_SM + kk + koff];
#pragma unroll
        for (int i = 0; i < 2; ++i) {
          const int ar = ((jt0 + i) * 16 + ln) * 64 + kk + koff;
          bf8v a1 = *(const bf8v*)&ws[OWF1 + ar];
          bf8v a2 = *(const bf8v*)&ws[OWF2 + ar];
          aF1[i][0] = MFMA(a1, b0, aF1[i][0]);
          aF1[i][1] = MFMA(a1, b1, aF1[i][1]);
          aF2[i][0] = MFMA(a2, b0, aF2[i][0]);
          aF2[i][1] = MFMA(a2, b1, aF2[i][1]);
        }
      }
      // epilogue: write f1/f2 (pre-tanh), seed acc1/acc2 with tanh(feed)+bias, seed acc3 with bias
#pragma unroll
      for (int i = 0; i < 2; ++i) {
#pragma unroll
        for (int mt = 0; mt < 2; ++mt) {
          int j0 = (jt0 + i) * 16 + quad * 4;
          int m  = mt * 16 + ln;
          size_t rowoff = ((size_t)t * B_TOT + m0 + m) * 256 + j0;
          nt_st4(out + O_F1 + rowoff, aF1[i][mt]);
          nt_st4(out + O_F2 + rowoff, aF2[i][mt]);
          f4v t1, t2;
#pragma unroll
          for (int r = 0; r < 4; ++r) {
            t1[r] = fast_tanh(aF1[i][mt][r]) + bih1v[i][r];
            t2[r] = fast_tanh(aF2[i][mt][r]) + bih2v[i][r];
          }
          acc1[i][mt] = t1; acc2[i][mt] = t2; acc3[i][mt] = b3shv[i];
        }
      }
    }
    __syncthreads();  // SYNC1: xs ready

    // ======== S1: h1n/h2n GEMMs (ih from xs, hh from hs1/hs2) + hh3 into acc3 ========
#pragma unroll
    for (int kk = 0; kk < 64; kk += 32) {
      bf8v b0 = *(const bf8v*)&xs[ln * LDS_SM + kk + koff];
      bf8v b1 = *(const bf8v*)&xs[(16 + ln) * LDS_SM + kk + koff];
#pragma unroll
      for (int i = 0; i < 2; ++i) {
        const int ar = ((jt0 + i) * 16 + ln) * 64 + kk + koff;
        bf8v a1 = *(const bf8v*)&ws[OW1I + ar];
        bf8v a2 = *(const bf8v*)&ws[OW2I + ar];
        acc1[i][0] = MFMA(a1, b0, acc1[i][0]);
        acc1[i][1] = MFMA(a1, b1, acc1[i][1]);
        acc2[i][0] = MFMA(a2, b0, acc2[i][0]);
        acc2[i][1] = MFMA(a2, b1, acc2[i][1]);
      }
    }
#pragma unroll
    for (int kk = 0; kk < 256; kk += 32) {
      bf8v q1a = *(const bf8v*)&hs1[ln * LDH + kk + koff];
      bf8v q1b = *(const bf8v*)&hs1[(16 + ln) * LDH + kk + koff];
      bf8v q2a = *(const bf8v*)&hs2[ln * LDH + kk + koff];
      bf8v q2b = *(const bf8v*)&hs2[(16 + ln) * LDH + kk + koff];
      bf8v q3a = *(const bf8v*)&hs3[ln * LDH + kk + koff];
      bf8v q3b = *(const bf8v*)&hs3[(16 + ln) * LDH + kk + koff];
#pragma unroll
      for (int i = 0; i < 2; ++i) {
        const int ar = ((jt0 + i) * 16 + ln) * 256 + kk + koff;
        bf8v a1 = *(const bf8v*)&ws[OW1H + ar];
        bf8v a2 = *(const bf8v*)&ws[OW2H + ar];
        bf8v a3 = *(const bf8v*)&ws[OW3H + ar];
        acc1[i][0] = MFMA(a1, q1a, acc1[i][0]);
        acc1[i][1] = MFMA(a1, q1b, acc1[i][1]);
        acc2[i][0] = MFMA(a2, q2a, acc2[i][0]);
        acc2[i][1] = MFMA(a2, q2b, acc2[i][1]);
        acc3[i][0] = MFMA(a3, q3a, acc3[i][0]);
        acc3[i][1] = MFMA(a3, q3b, acc3[i][1]);
      }
    }
#pragma unroll
    for (int i = 0; i < 2; ++i) {
#pragma unroll
      for (int mt = 0; mt < 2; ++mt) {
#pragma unroll
        for (int r = 0; r < 4; ++r) {
          acc1[i][mt][r] = fast_tanh(acc1[i][mt][r]);
          acc2[i][mt][r] = fast_tanh(acc2[i][mt][r]);
        }
      }
    }
    if (t == T_STEPS - 1) {
#pragma unroll
      for (int i = 0; i < 2; ++i) {
#pragma unroll
        for (int mt = 0; mt < 2; ++mt) {
          int j0 = (jt0 + i) * 16 + quad * 4;
          int m  = mt * 16 + ln;
          nt_st4(out + O_H1 + (size_t)(m0 + m) * 256 + j0, acc1[i][mt]);
          nt_st4(out + O_H2 + (size_t)(m0 + m) * 256 + j0, acc2[i][mt]);
        }
      }
    }
    __syncthreads();  // SYNC2: all reads of old hs1/hs2/hs3 done

    // ======== S2: write back new h1/h2 states ========
#pragma unroll
    for (int i = 0; i < 2; ++i) {
#pragma unroll
      for (int mt = 0; mt < 2; ++mt) {
        int j0 = (jt0 + i) * 16 + quad * 4;
        int m  = mt * 16 + ln;
        store_bf4(&hs1[m * LDH + j0], acc1[i][mt]);
        store_bf4(&hs2[m * LDH + j0], acc2[i][mt]);
      }
    }
    __syncthreads();  // SYNC3: new hs1/hs2 ready

    // ======== S3: out1 (waves 0-3) / out2 (waves 4-7), N=64, K=256 ========
    {
      const ushort_t* hsrc = isOut2 ? hs2 : hs1;
      const int wbase = isOut2 ? OW2O : OW1O;
      f4v aO[2];
      aO[0] = bo3v; aO[1] = bo3v;
#pragma unroll
      for (int kk = 0; kk < 256; kk += 32) {
        bf8v b0 = *(const bf8v*)&hsrc[ln * LDH + kk + koff];
        bf8v b1 = *(const bf8v*)&hsrc[(16 + ln) * LDH + kk + koff];
        bf8v a  = *(const bf8v*)&ws[wbase + (jto3 * 16 + ln) * 256 + kk + koff];
        aO[0] = MFMA(a, b0, aO[0]);
        aO[1] = MFMA(a, b1, aO[1]);
      }
#pragma unroll
      for (int mt = 0; mt < 2; ++mt) {
#pragma unroll
        for (int r = 0; r < 4; ++r) aO[mt][r] = fast_tanh(aO[mt][r]);
        int m = mt * 16 + ln;
        size_t ob = ((size_t)t * B_TOT + m0 + m) * 64 + j0o3;
        nt_st4(out + (isOut2 ? O_O2 : O_O1) + ob, aO[mt]);
        store_bf4(&mid[m * LDMID + (isOut2 ? 64 : 0) + j0o3], aO[mt]);
      }
    }
    __syncthreads();  // SYNC4: mid ready

    // ======== S4: acc3 += W3i_perm x mid (K=160); tanh; write hs3 ========
#pragma unroll
    for (int kk = 0; kk < 160; kk += 32) {
      bf8v b0 = *(const bf8v*)&mid[ln * LDMID + kk + koff];
      bf8v b1 = *(const bf8v*)&mid[(16 + ln) * LDMID + kk + koff];
#pragma unroll
      for (int i = 0; i < 2; ++i) {
        bf8v a = *(const bf8v*)&ws[OW3I + ((jt0 + i) * 16 + ln) * 160 + kk + koff];
        acc3[i][0] = MFMA(a, b0, acc3[i][0]);
        acc3[i][1] = MFMA(a, b1, acc3[i][1]);
      }
    }
#pragma unroll
    for (int i = 0; i < 2; ++i) {
#pragma unroll
      for (int mt = 0; mt < 2; ++mt) {
#pragma unroll
        for (int r = 0; r < 4; ++r) acc3[i][mt][r] = fast_tanh(acc3[i][mt][r]);
        int j0 = (jt0 + i) * 16 + quad * 4;
        int m  = mt * 16 + ln;
        if (t == T_STEPS - 1)
          nt_st4(out + O_H3 + (size_t)(m0 + m) * 256 + j0, acc3[i][mt]);
        store_bf4(&hs3[m * LDH + j0], acc3[i][mt]);  // old hs3 readers finished at S1 (SYNC2+)
      }
    }
    __syncthreads();  // SYNC5: new hs3 ready

    // ======== S5: o = h3n @ W3o.T + b3o (N=64); -> h4s, ofa, ofs, (h4 final) ========
    {
      f4v aO = b3ov;
#pragma unroll
      for (int kk = 0; kk < 256; kk += 32) {
        bf8v b = *(const bf8v*)&hs3[mo5 * LDH + kk + koff];
        bf8v a = *(const bf8v*)&ws[OW3O + (jto5 * 16 + ln) * 256 + kk + koff];
        aO = MFMA(a, b, aO);
      }
      store_bf4(&h4s[mo5 * LDS_SM + j0o5], aO);  // h4s readers (S0) finished long ago
      if (t == T_STEPS - 1)
        nt_st4(out + O_H4 + (size_t)(m0 + mo5) * 64 + j0o5, aO);
      f4v rl;
#pragma unroll
      for (int r = 0; r < 4; ++r) rl[r] = fmaxf(aO[r], 0.0f);
      nt_st4(out + O_OFA + ((size_t)t * B_TOT + m0 + mo5) * 64 + j0o5, rl);
      store_bf4(&ofs[mo5 * LDS_SM + j0o5], rl);
    }
    __syncthreads();  // SYNC6: ofs/h4s ready

    // ======== S6: outf = relu(o) @ Wfc.T + bfc -> oseq (waves 0,1 only) ========
    if (w < 2) {
      f4v aFc;
      aFc[0] = (quad == 0) ? bfcv0 : 0.0f;
      aFc[1] = (quad == 0) ? bfcv1 : 0.0f;
      aFc[2] = 0.0f; aFc[3] = 0.0f;
#pragma unroll
      for (int kk = 0; kk < 64; kk += 32) {
        bf8v b = *(const bf8v*)&ofs[(w * 16 + ln) * LDS_SM + kk + koff];
        bf8v a = *(const bf8v*)&ws[OWFC + ln * 64 + kk + koff];
        aFc = MFMA(a, b, aFc);
      }
      if (quad == 0) {
        float* po = out + O_OSEQ + ((size_t)t * B_TOT + m0 + w * 16 + ln) * 2;
        __builtin_nontemporal_store(aFc[0], po);
        __builtin_nontemporal_store(aFc[1], po + 1);
      }
    }
    // no barrier needed: next S0 writes xs (last read S1, covered by SYNC2+)
    // and reads h4s (written S5, covered by SYNC6)
  }
}

extern "C" void kernel_launch(void* const* d_in, const int* in_sizes, int n_in,
                              void* d_out, int out_size, void* d_ws, size_t ws_size,
                              hipStream_t stream) {
  const float* x   = (const float*)d_in[0];
  const float* cue = (const float*)d_in[1];
  const float* hc1 = (const float*)d_in[2];
  const float* hc2 = (const float*)d_in[3];
  const float* hc3 = (const float*)d_in[4];
  const float* hc4 = (const float*)d_in[5];
  const float* W1i = (const float*)d_in[6];
  const float* b1i = (const float*)d_in[7];
  const float* W1h = (const float*)d_in[8];
  const float* b1h = (const float*)d_in[9];
  const float* Wf1 = (const float*)d_in[10];
  const float* bf1 = (const float*)d_in[11];
  const float* W1o = (const float*)d_in[12];
  const float* b1o = (const float*)d_in[13];
  const float* W2i = (const float*)d_in[14];
  const float* b2i = (const float*)d_in[15];
  const float* W2h = (const float*)d_in[16];
  const float* b2h = (const float*)d_in[17];
  const float* Wf2 = (const float*)d_in[18];
  const float* bf2 = (const float*)d_in[19];
  const float* W2o = (const float*)d_in[20];
  const float* b2o = (const float*)d_in[21];
  const float* W3i = (const float*)d_in[22];
  const float* b3i = (const float*)d_in[23];
  const float* W3h = (const float*)d_in[24];
  const float* b3h = (const float*)d_in[25];
  const float* W3o = (const float*)d_in[26];
  const float* b3o = (const float*)d_in[27];
  const float* Wfc = (const float*)d_in[28];
  const float* bfc = (const float*)d_in[29];

  ushort_t* ws = (ushort_t*)d_ws;
  float* out = (float*)d_out;

  prep_kernel<<<(WS_TOTAL + 511) / 512, 512, 0, stream>>>(
      W1i, W1h, Wf1, W1o, W2i, W2h, Wf2, W2o, W3i, W3h, W3o, Wfc, ws);

  rnn_kernel<<<B_TOT / M_TILE, 512, 0, stream>>>(
      x, cue, hc1, hc2, hc3, hc4,
      b1i, b1h, bf1, b1o, b2i, b2h, bf2, b2o, b3i, b3h, b3o, bfc,
      ws, out);
}

// Round 4
// 968.208 us; speedup vs baseline: 1.7511x; 1.0205x over previous
//
#include <hip/hip_runtime.h>

typedef unsigned short ushort_t;
typedef __attribute__((ext_vector_type(8))) __bf16 bf8v;
typedef __attribute__((ext_vector_type(4))) float f4v;
typedef __attribute__((ext_vector_type(4))) unsigned short us4v;

#define MFMA(a, b, c) __builtin_amdgcn_mfma_f32_16x16x32_bf16((a), (b), (c), 0, 0, 0)

#define B_TOT 8192
#define T_STEPS 16
#define M_TILE 32
#define LDH 264      // 256 + 8 pad
#define LDS_SM 72    // 64 + 8 pad
#define LDMID 168    // 160 + 8 pad

// bf16 weight workspace offsets (ushort units)
#define OW1I 0
#define OW1H 16384
#define OWF1 81920
#define OW1O 98304
#define OW2I 114688
#define OW2H 131072
#define OWF2 196608
#define OW2O 212992
#define OW3I 229376   // [256][160] permuted
#define OW3H 270336
#define OW3O 335872
#define OWFC 352256   // [16][64], rows 2..15 zero
#define WS_TOTAL 353280

// output offsets (float units)
#define O_OSEQ 0
#define O_H1   262144
#define O_H2   2359296
#define O_H3   4456448
#define O_H4   6553600
#define O_O1   7077888
#define O_O2   15466496
#define O_CUE  23855104
#define O_F1   24117248
#define O_F2   57671680
#define O_OFA  91226112

__device__ __forceinline__ ushort_t f2bf(float f) {
  union { float f; unsigned u; } v; v.f = f;
  unsigned r = v.u + 0x7fffu + ((v.u >> 16) & 1u);
  return (ushort_t)(r >> 16);
}

__device__ __forceinline__ float fast_tanh(float x) {
  float e = __expf(2.0f * x);
  return 1.0f - 2.0f * __builtin_amdgcn_rcpf(e + 1.0f);
}

__device__ __forceinline__ void store_bf4(ushort_t* p, f4v v) {
  us4v q;
  q[0] = f2bf(v[0]); q[1] = f2bf(v[1]); q[2] = f2bf(v[2]); q[3] = f2bf(v[3]);
  *(us4v*)p = q;
}

__device__ __forceinline__ void nt_st4(float* p, f4v v) {
  __builtin_nontemporal_store(v, (f4v*)p);
}
__device__ __forceinline__ f4v nt_ld4(const float* p) {
  return __builtin_nontemporal_load((const f4v*)p);
}

__global__ void prep_kernel(const float* __restrict__ W1i, const float* __restrict__ W1h,
                            const float* __restrict__ Wf1, const float* __restrict__ W1o,
                            const float* __restrict__ W2i, const float* __restrict__ W2h,
                            const float* __restrict__ Wf2, const float* __restrict__ W2o,
                            const float* __restrict__ W3i, const float* __restrict__ W3h,
                            const float* __restrict__ W3o, const float* __restrict__ Wfc,
                            ushort_t* __restrict__ ws) {
  int i = blockIdx.x * blockDim.x + threadIdx.x;
  if (i >= WS_TOTAL) return;
  float v;
  if (i < OW1H)       v = W1i[i - OW1I];
  else if (i < OWF1)  v = W1h[i - OW1H];
  else if (i < OW1O)  v = Wf1[i - OWF1];
  else if (i < OW2I)  v = W1o[i - OW1O];
  else if (i < OW2H)  v = W2i[i - OW2I];
  else if (i < OWF2)  v = W2h[i - OW2H];
  else if (i < OW2O)  v = Wf2[i - OWF2];
  else if (i < OW3I)  v = W2o[i - OW2O];
  else if (i < OW3H) {
    int idx = i - OW3I; int j = idx / 160; int k = idx - j * 160;
    if (k < 64)       v = W3i[j * 130 + 2 + k];
    else if (k < 128) v = W3i[j * 130 + 66 + (k - 64)];
    else if (k < 130) v = W3i[j * 130 + (k - 128)];
    else              v = 0.0f;
  }
  else if (i < OW3O)  v = W3h[i - OW3H];
  else if (i < OWFC)  v = W3o[i - OW3O];
  else {
    int idx = i - OWFC; int j = idx / 64; int k = idx - j * 64;
    v = (j < 2) ? Wfc[j * 64 + k] : 0.0f;
  }
  ws[i] = f2bf(v);
}

// M_TILE=32, 256 blocks = 1 block/CU, 8 waves.
// Cross-barrier weight prefetch: each phase's ws A-operands are loaded into
// registers during the PREVIOUS phase (ws is read-only; only source-level
// barrier placement prevented the compiler from doing this hoist itself).
__launch_bounds__(512, 2)
__global__ void rnn_kernel(const float* __restrict__ x, const float* __restrict__ cue,
                           const float* __restrict__ hc1, const float* __restrict__ hc2,
                           const float* __restrict__ hc3, const float* __restrict__ hc4,
                           const float* __restrict__ b1i, const float* __restrict__ b1h,
                           const float* __restrict__ bf1p, const float* __restrict__ b1o,
                           const float* __restrict__ b2i, const float* __restrict__ b2h,
                           const float* __restrict__ bf2p, const float* __restrict__ b2o,
                           const float* __restrict__ b3i, const float* __restrict__ b3h,
                           const float* __restrict__ b3o, const float* __restrict__ bfc,
                           const ushort_t* __restrict__ ws, float* __restrict__ out) {
  __shared__ ushort_t hs1[M_TILE * LDH], hs2[M_TILE * LDH], hs3[M_TILE * LDH];
  __shared__ ushort_t h4s[M_TILE * LDS_SM], xs[M_TILE * LDS_SM], ofs[M_TILE * LDS_SM];
  __shared__ ushort_t mid[M_TILE * LDMID];

  const int tid  = threadIdx.x;
  const int m0   = blockIdx.x * M_TILE;
  const int lane = tid & 63;
  const int w    = tid >> 6;
  const int ln   = lane & 15;
  const int quad = lane >> 4;
  const int koff = quad * 8;
  const int jt0  = 2 * w;

  // ---------------- init: states -> LDS ----------------
  for (int i = tid; i < M_TILE * 64; i += 512) {
    int m = i >> 6, j4 = (i & 63) * 4;
    store_bf4(&hs1[m * LDH + j4], nt_ld4(&hc1[(size_t)(m0 + m) * 256 + j4]));
    store_bf4(&hs2[m * LDH + j4], nt_ld4(&hc2[(size_t)(m0 + m) * 256 + j4]));
    store_bf4(&hs3[m * LDH + j4], nt_ld4(&hc3[(size_t)(m0 + m) * 256 + j4]));
  }
  {
    int m = tid >> 4, j4 = (tid & 15) * 4;
    store_bf4(&h4s[m * LDS_SM + j4], nt_ld4(&hc4[(size_t)(m0 + m) * 64 + j4]));
  }
  for (int i = tid; i < M_TILE * LDMID; i += 512) mid[i] = 0;
  {
    int t = tid >> 5, r = tid & 31;
    float c = cue[m0 + r];
    float* oc = out + O_CUE + ((size_t)t * B_TOT + m0 + r) * 2;
    __builtin_nontemporal_store(c * 10.0f, oc);
    __builtin_nontemporal_store(10.0f * fabsf(c - 1.0f), oc + 1);
  }
  __syncthreads();
  if (tid < M_TILE) {
    float c = cue[m0 + tid];
    mid[tid * LDMID + 128] = f2bf(c * 10.0f);
    mid[tid * LDMID + 129] = f2bf(10.0f * fabsf(c - 1.0f));
  }

  // ---------------- bias registers (t-invariant) ----------------
  f4v bf1v[2], bf2v[2], bih1v[2], bih2v[2], b3shv[2];
#pragma unroll
  for (int i = 0; i < 2; ++i) {
    int j0 = (jt0 + i) * 16 + quad * 4;
#pragma unroll
    for (int r = 0; r < 4; ++r) {
      bf1v[i][r]  = bf1p[j0 + r];
      bf2v[i][r]  = bf2p[j0 + r];
      bih1v[i][r] = b1i[j0 + r] + b1h[j0 + r];
      bih2v[i][r] = b2i[j0 + r] + b2h[j0 + r];
      b3shv[i][r] = b3i[j0 + r] + b3h[j0 + r];
    }
  }
  const int jto3 = w & 3;
  const int j0o3 = jto3 * 16 + quad * 4;
  const bool isOut2 = (w >= 4);
  f4v bo3v;
#pragma unroll
  for (int r = 0; r < 4; ++r) bo3v[r] = isOut2 ? b2o[j0o3 + r] : b1o[j0o3 + r];
  const int jto5 = w >> 1;
  const int j0o5 = jto5 * 16 + quad * 4;
  const int mo5  = (w & 1) * 16 + ln;
  f4v b3ov;
#pragma unroll
  for (int r = 0; r < 4; ++r) b3ov[r] = b3o[j0o5 + r];
  const float bfcv0 = bfc[0], bfcv1 = bfc[1];

  __syncthreads();

  // ---------------- prefetch register state ----------------
  f4v acc1[2][2], acc2[2][2], acc3[2][2];
  bf8v pF[2][2][2];   // S0 A: [kq][i][{Wf1,Wf2}]      (loaded in S5 / pre-loop)
  bf8v pIH[2][2][2];  // S1 ih A: [kq][i][{W1i,W2i}]   (loaded in S0)
  bf8v Ah[2][2][3];   // S1 hh 2-stage pipe: [buf][i][{W1h,W2h,W3h}] (stage0 loaded in S0)
  bf8v pO[8];         // S3 A per kk                    (loaded in S1 epilogue)
  bf8v pI3[5][2];     // S4 A: [kk][i]                  (loaded in S3)
  bf8v pO3[8];        // S5 A per kk                    (loaded in S4)
  bf8v pFc[2];        // S6 A                           (loaded in S5, w<2)
  f4v  xv;            // next x tile row                (loaded in S5 / pre-loop)

#define LOAD_PF() do { \
  _Pragma("unroll") for (int kq = 0; kq < 2; ++kq) \
  _Pragma("unroll") for (int i = 0; i < 2; ++i) { \
    const int ar = ((jt0 + i) * 16 + ln) * 64 + kq * 32 + koff; \
    pF[kq][i][0] = *(const bf8v*)&ws[OWF1 + ar]; \
    pF[kq][i][1] = *(const bf8v*)&ws[OWF2 + ar]; \
  } } while (0)

#define LOAD_XV(tt) do { \
  int r_ = tid >> 4, c4_ = (tid & 15) * 4; \
  xv = nt_ld4(x + ((size_t)(tt) * B_TOT + m0 + r_) * 64 + c4_); \
  } while (0)

  LOAD_PF();
  LOAD_XV(0);

  for (int t = 0; t < T_STEPS; ++t) {
    // ======== S0: xs store; prefetch S1 operands; feed GEMMs (A = pF) ========
    {
      int r = tid >> 4, c4 = (tid & 15) * 4;
      store_bf4(&xs[r * LDS_SM + c4], xv);
    }
    // prefetch S1-ih A
#pragma unroll
    for (int kq = 0; kq < 2; ++kq)
#pragma unroll
      for (int i = 0; i < 2; ++i) {
        const int ar = ((jt0 + i) * 16 + ln) * 64 + kq * 32 + koff;
        pIH[kq][i][0] = *(const bf8v*)&ws[OW1I + ar];
        pIH[kq][i][1] = *(const bf8v*)&ws[OW2I + ar];
      }
    // prefetch S1-hh stage 0 (kk = 0)
#pragma unroll
    for (int i = 0; i < 2; ++i) {
      const int ar = ((jt0 + i) * 16 + ln) * 256 + koff;
      Ah[0][i][0] = *(const bf8v*)&ws[OW1H + ar];
      Ah[0][i][1] = *(const bf8v*)&ws[OW2H + ar];
      Ah[0][i][2] = *(const bf8v*)&ws[OW3H + ar];
    }
    {
      f4v aF1[2][2], aF2[2][2];
#pragma unroll
      for (int i = 0; i < 2; ++i) {
#pragma unroll
        for (int mt = 0; mt < 2; ++mt) { aF1[i][mt] = bf1v[i]; aF2[i][mt] = bf2v[i]; }
      }
#pragma unroll
      for (int kq = 0; kq < 2; ++kq) {
        const int kk = kq * 32;
        bf8v b0 = *(const bf8v*)&h4s[ln * LDS_SM + kk + koff];
        bf8v b1 = *(const bf8v*)&h4s[(16 + ln) * LDS_SM + kk + koff];
#pragma unroll
        for (int i = 0; i < 2; ++i) {
          aF1[i][0] = MFMA(pF[kq][i][0], b0, aF1[i][0]);
          aF1[i][1] = MFMA(pF[kq][i][0], b1, aF1[i][1]);
          aF2[i][0] = MFMA(pF[kq][i][1], b0, aF2[i][0]);
          aF2[i][1] = MFMA(pF[kq][i][1], b1, aF2[i][1]);
        }
      }
#pragma unroll
      for (int i = 0; i < 2; ++i) {
#pragma unroll
        for (int mt = 0; mt < 2; ++mt) {
          int j0 = (jt0 + i) * 16 + quad * 4;
          int m  = mt * 16 + ln;
          size_t rowoff = ((size_t)t * B_TOT + m0 + m) * 256 + j0;
          nt_st4(out + O_F1 + rowoff, aF1[i][mt]);
          nt_st4(out + O_F2 + rowoff, aF2[i][mt]);
          f4v t1, t2;
#pragma unroll
          for (int r = 0; r < 4; ++r) {
            t1[r] = fast_tanh(aF1[i][mt][r]) + bih1v[i][r];
            t2[r] = fast_tanh(aF2[i][mt][r]) + bih2v[i][r];
          }
          acc1[i][mt] = t1; acc2[i][mt] = t2; acc3[i][mt] = b3shv[i];
        }
      }
    }
    __syncthreads();  // SYNC1: xs ready

    // ======== S1: ih (A = pIH) + hh (2-stage pipelined, stage0 preloaded) ========
#pragma unroll
    for (int kq = 0; kq < 2; ++kq) {
      const int kk = kq * 32;
      bf8v b0 = *(const bf8v*)&xs[ln * LDS_SM + kk + koff];
      bf8v b1 = *(const bf8v*)&xs[(16 + ln) * LDS_SM + kk + koff];
#pragma unroll
      for (int i = 0; i < 2; ++i) {
        acc1[i][0] = MFMA(pIH[kq][i][0], b0, acc1[i][0]);
        acc1[i][1] = MFMA(pIH[kq][i][0], b1, acc1[i][1]);
        acc2[i][0] = MFMA(pIH[kq][i][1], b0, acc2[i][0]);
        acc2[i][1] = MFMA(pIH[kq][i][1], b1, acc2[i][1]);
      }
    }
#pragma unroll
    for (int kk = 0; kk < 256; kk += 32) {
      const int cur = (kk >> 5) & 1;
      if (kk < 224) {
#pragma unroll
        for (int i = 0; i < 2; ++i) {
          const int ar = ((jt0 + i) * 16 + ln) * 256 + kk + 32 + koff;
          Ah[cur ^ 1][i][0] = *(const bf8v*)&ws[OW1H + ar];
          Ah[cur ^ 1][i][1] = *(const bf8v*)&ws[OW2H + ar];
          Ah[cur ^ 1][i][2] = *(const bf8v*)&ws[OW3H + ar];
        }
      }
      bf8v q1a = *(const bf8v*)&hs1[ln * LDH + kk + koff];
      bf8v q1b = *(const bf8v*)&hs1[(16 + ln) * LDH + kk + koff];
      bf8v q2a = *(const bf8v*)&hs2[ln * LDH + kk + koff];
      bf8v q2b = *(const bf8v*)&hs2[(16 + ln) * LDH + kk + koff];
      bf8v q3a = *(const bf8v*)&hs3[ln * LDH + kk + koff];
      bf8v q3b = *(const bf8v*)&hs3[(16 + ln) * LDH + kk + koff];
#pragma unroll
      for (int i = 0; i < 2; ++i) {
        acc1[i][0] = MFMA(Ah[cur][i][0], q1a, acc1[i][0]);
        acc1[i][1] = MFMA(Ah[cur][i][0], q1b, acc1[i][1]);
        acc2[i][0] = MFMA(Ah[cur][i][1], q2a, acc2[i][0]);
        acc2[i][1] = MFMA(Ah[cur][i][1], q2b, acc2[i][1]);
        acc3[i][0] = MFMA(Ah[cur][i][2], q3a, acc3[i][0]);
        acc3[i][1] = MFMA(Ah[cur][i][2], q3b, acc3[i][1]);
      }
    }
    // prefetch S3 A (crosses SYNC2+SYNC3)
    {
      const int wbase = isOut2 ? OW2O : OW1O;
#pragma unroll
      for (int kq = 0; kq < 8; ++kq)
        pO[kq] = *(const bf8v*)&ws[wbase + (jto3 * 16 + ln) * 256 + kq * 32 + koff];
    }
#pragma unroll
    for (int i = 0; i < 2; ++i) {
#pragma unroll
      for (int mt = 0; mt < 2; ++mt) {
#pragma unroll
        for (int r = 0; r < 4; ++r) {
          acc1[i][mt][r] = fast_tanh(acc1[i][mt][r]);
          acc2[i][mt][r] = fast_tanh(acc2[i][mt][r]);
        }
      }
    }
    if (t == T_STEPS - 1) {
#pragma unroll
      for (int i = 0; i < 2; ++i) {
#pragma unroll
        for (int mt = 0; mt < 2; ++mt) {
          int j0 = (jt0 + i) * 16 + quad * 4;
          int m  = mt * 16 + ln;
          nt_st4(out + O_H1 + (size_t)(m0 + m) * 256 + j0, acc1[i][mt]);
          nt_st4(out + O_H2 + (size_t)(m0 + m) * 256 + j0, acc2[i][mt]);
        }
      }
    }
    __syncthreads();  // SYNC2

    // ======== S2: write back new h1/h2 ========
#pragma unroll
    for (int i = 0; i < 2; ++i) {
#pragma unroll
      for (int mt = 0; mt < 2; ++mt) {
        int j0 = (jt0 + i) * 16 + quad * 4;
        int m  = mt * 16 + ln;
        store_bf4(&hs1[m * LDH + j0], acc1[i][mt]);
        store_bf4(&hs2[m * LDH + j0], acc2[i][mt]);
      }
    }
    __syncthreads();  // SYNC3

    // ======== S3: out1/out2 (A = pO); prefetch S4's W3i ========
    {
#pragma unroll
      for (int kq = 0; kq < 5; ++kq)
#pragma unroll
        for (int i = 0; i < 2; ++i)
          pI3[kq][i] = *(const bf8v*)&ws[OW3I + ((jt0 + i) * 16 + ln) * 160 + kq * 32 + koff];

      const ushort_t* hsrc = isOut2 ? hs2 : hs1;
      f4v aO[2];
      aO[0] = bo3v; aO[1] = bo3v;
#pragma unroll
      for (int kq = 0; kq < 8; ++kq) {
        const int kk = kq * 32;
        bf8v b0 = *(const bf8v*)&hsrc[ln * LDH + kk + koff];
        bf8v b1 = *(const bf8v*)&hsrc[(16 + ln) * LDH + kk + koff];
        aO[0] = MFMA(pO[kq], b0, aO[0]);
        aO[1] = MFMA(pO[kq], b1, aO[1]);
      }
#pragma unroll
      for (int mt = 0; mt < 2; ++mt) {
#pragma unroll
        for (int r = 0; r < 4; ++r) aO[mt][r] = fast_tanh(aO[mt][r]);
        int m = mt * 16 + ln;
        size_t ob = ((size_t)t * B_TOT + m0 + m) * 64 + j0o3;
        nt_st4(out + (isOut2 ? O_O2 : O_O1) + ob, aO[mt]);
        store_bf4(&mid[m * LDMID + (isOut2 ? 64 : 0) + j0o3], aO[mt]);
      }
    }
    __syncthreads();  // SYNC4: mid ready

    // ======== S4: acc3 += W3i x mid (A = pI3); prefetch S5's W3o ========
#pragma unroll
    for (int kq = 0; kq < 8; ++kq)
      pO3[kq] = *(const bf8v*)&ws[OW3O + (jto5 * 16 + ln) * 256 + kq * 32 + koff];
#pragma unroll
    for (int kq = 0; kq < 5; ++kq) {
      const int kk = kq * 32;
      bf8v b0 = *(const bf8v*)&mid[ln * LDMID + kk + koff];
      bf8v b1 = *(const bf8v*)&mid[(16 + ln) * LDMID + kk + koff];
#pragma unroll
      for (int i = 0; i < 2; ++i) {
        acc3[i][0] = MFMA(pI3[kq][i], b0, acc3[i][0]);
        acc3[i][1] = MFMA(pI3[kq][i], b1, acc3[i][1]);
      }
    }
#pragma unroll
    for (int i = 0; i < 2; ++i) {
#pragma unroll
      for (int mt = 0; mt < 2; ++mt) {
#pragma unroll
        for (int r = 0; r < 4; ++r) acc3[i][mt][r] = fast_tanh(acc3[i][mt][r]);
        int j0 = (jt0 + i) * 16 + quad * 4;
        int m  = mt * 16 + ln;
        if (t == T_STEPS - 1)
          nt_st4(out + O_H3 + (size_t)(m0 + m) * 256 + j0, acc3[i][mt]);
        store_bf4(&hs3[m * LDH + j0], acc3[i][mt]);
      }
    }
    __syncthreads();  // SYNC5: new hs3 ready

    // ======== S5: o GEMM (A = pO3); prefetch pF (next S0), xv (next t), pFc ========
    LOAD_PF();
    LOAD_XV(t + 1 < T_STEPS ? t + 1 : T_STEPS - 1);
    if (w < 2) {
      pFc[0] = *(const bf8v*)&ws[OWFC + ln * 64 + koff];
      pFc[1] = *(const bf8v*)&ws[OWFC + ln * 64 + 32 + koff];
    }
    {
      f4v aO = b3ov;
#pragma unroll
      for (int kq = 0; kq < 8; ++kq) {
        const int kk = kq * 32;
        bf8v b = *(const bf8v*)&hs3[mo5 * LDH + kk + koff];
        aO = MFMA(pO3[kq], b, aO);
      }
      store_bf4(&h4s[mo5 * LDS_SM + j0o5], aO);
      if (t == T_STEPS - 1)
        nt_st4(out + O_H4 + (size_t)(m0 + mo5) * 64 + j0o5, aO);
      f4v rl;
#pragma unroll
      for (int r = 0; r < 4; ++r) rl[r] = fmaxf(aO[r], 0.0f);
      nt_st4(out + O_OFA + ((size_t)t * B_TOT + m0 + mo5) * 64 + j0o5, rl);
      store_bf4(&ofs[mo5 * LDS_SM + j0o5], rl);
    }
    __syncthreads();  // SYNC6: ofs/h4s ready

    // ======== S6: outf (A = pFc, waves 0,1) ========
    if (w < 2) {
      f4v aFc;
      aFc[0] = (quad == 0) ? bfcv0 : 0.0f;
      aFc[1] = (quad == 0) ? bfcv1 : 0.0f;
      aFc[2] = 0.0f; aFc[3] = 0.0f;
#pragma unroll
      for (int kq = 0; kq < 2; ++kq) {
        const int kk = kq * 32;
        bf8v b = *(const bf8v*)&ofs[(w * 16 + ln) * LDS_SM + kk + koff];
        aFc = MFMA(pFc[kq], b, aFc);
      }
      if (quad == 0) {
        float* po = out + O_OSEQ + ((size_t)t * B_TOT + m0 + w * 16 + ln) * 2;
        __builtin_nontemporal_store(aFc[0], po);
        __builtin_nontemporal_store(aFc[1], po + 1);
      }
    }
    // no barrier: next S0 writes xs (readers done at SYNC2+), reads h4s (SYNC6)
  }
#undef LOAD_PF
#undef LOAD_XV
}

extern "C" void kernel_launch(void* const* d_in, const int* in_sizes, int n_in,
                              void* d_out, int out_size, void* d_ws, size_t ws_size,
                              hipStream_t stream) {
  const float* x   = (const float*)d_in[0];
  const float* cue = (const float*)d_in[1];
  const float* hc1 = (const float*)d_in[2];
  const float* hc2 = (const float*)d_in[3];
  const float* hc3 = (const float*)d_in[4];
  const float* hc4 = (const float*)d_in[5];
  const float* W1i = (const float*)d_in[6];
  const float* b1i = (const float*)d_in[7];
  const float* W1h = (const float*)d_in[8];
  const float* b1h = (const float*)d_in[9];
  const float* Wf1 = (const float*)d_in[10];
  const float* bf1 = (const float*)d_in[11];
  const float* W1o = (const float*)d_in[12];
  const float* b1o = (const float*)d_in[13];
  const float* W2i = (const float*)d_in[14];
  const float* b2i = (const float*)d_in[15];
  const float* W2h = (const float*)d_in[16];
  const float* b2h = (const float*)d_in[17];
  const float* Wf2 = (const float*)d_in[18];
  const float* bf2 = (const float*)d_in[19];
  const float* W2o = (const float*)d_in[20];
  const float* b2o = (const float*)d_in[21];
  const float* W3i = (const float*)d_in[22];
  const float* b3i = (const float*)d_in[23];
  const float* W3h = (const float*)d_in[24];
  const float* b3h = (const float*)d_in[25];
  const float* W3o = (const float*)d_in[26];
  const float* b3o = (const float*)d_in[27];
  const float* Wfc = (const float*)d_in[28];
  const float* bfc = (const float*)d_in[29];

  ushort_t* ws = (ushort_t*)d_ws;
  float* out = (float*)d_out;

  prep_kernel<<<(WS_TOTAL + 511) / 512, 512, 0, stream>>>(
      W1i, W1h, Wf1, W1o, W2i, W2h, Wf2, W2o, W3i, W3h, W3o, Wfc, ws);

  rnn_kernel<<<B_TOT / M_TILE, 512, 0, stream>>>(
      x, cue, hc1, hc2, hc3, hc4,
      b1i, b1h, bf1, b1o, b2i, b2h, bf2, b2o, b3i, b3h, b3o, bfc,
      ws, out);
}